// Round 14
// baseline (5009.162 us; speedup 1.0000x reference)
//
#include <hip/hip_runtime.h>
#include <math.h>

#define TT 2048
#define NB 64
#define EE 256
#define HH 256
#define PJ 16    // j-partitions recorded in part[] (unchanged layout)
#define XLD 288  // swizzled row: 256 + 4 pad per 32 floats
#define RS1 280  // red_s kc stride
#define RS2 72   // red_s batch stride
#define RBOFF (8 * RS1)   // context-B offset within red_s

typedef float f32x4 __attribute__((ext_vector_type(4)));
typedef float f32x2 __attribute__((ext_vector_type(2)));

__device__ __forceinline__ float sigf(float x) { return 1.f / (1.f + expf(-x)); }

__device__ __forceinline__ unsigned long long packh(unsigned tag, float v) {
    union { float f; unsigned u; } c; c.f = v;
    return ((unsigned long long)tag << 32) | (unsigned long long)c.u;
}

// pk_fma: 2 independent fp32 FMAs per instruction (VOP3P). Bitwise identical
// to scalar v_fma_f32 per component; halves FMA issue count.
__device__ __forceinline__ void pkfma(f32x2& acc, f32x2 a, f32x2 b) {
    asm("v_pk_fma_f32 %0, %1, %2, %0" : "+v"(acc) : "v"(a), "v"(b));
}

// R19: R18 (champion: dual-context stagger, self-sufficient spins, 2
// barriers/step) + v_pk_fma_f32 packed fp32 FMAs. Each thread's 64 scalar
// FMAs per phase become 32 packed ones; accumulator pairs {x,y},{z,w} map
// exactly onto the existing horizontal-add tree -> bitwise identical.
// Everything else (schedule, spin protocol, staging, epilogues, red_s
// layout) is R18 verbatim. absmax must stay 0.
__global__ __launch_bounds__(512, 2)
void lstm_kernel(const int* __restrict__ sent, const float* __restrict__ emb,
                 const float* __restrict__ W_ih, const float* __restrict__ W_hh,
                 const float* __restrict__ b_ih, const float* __restrict__ b_hh,
                 const float* __restrict__ W_z,
                 unsigned long long* __restrict__ hbuf,
                 float* __restrict__ part)
{
    __shared__ __align__(16) float x_sw[6 * XLD]; // 0-1: A; 2-3: B par0; 4-5: B par1
    __shared__ __align__(16) float h_sw[4 * XLD]; // 0-1: A; 2-3: B
    __shared__ __align__(16) float red_s[2 * 8 * RS1];
    __shared__ __align__(16) float p_s[64];       // 0-31: A, 32-63: B
    extern __shared__ float dyn_pad[];            // occupancy pad

    const int tid  = threadIdx.x;
    if (tid == 0 && sent[0] < 0) ((volatile float*)dyn_pad)[0] = 0.f;

    // XCD-clustering swizzle (heuristic)
    const int xcd  = blockIdx.x & 7;
    const int slot = blockIdx.x >> 3;        // 0..31
    const int psys = xcd * 2 + (slot >> 4);  // 0..15 pair-system
    const int js   = slot & 15;              // j-slice
    const int bA0  = psys * 2;
    const int bB0  = 32 + psys * 2;
    const int j0   = js * 16;

    const int wv    = tid >> 6;              // 0..7
    const int lane  = tid & 63;
    const int bp    = wv & 1;                // batch within context
    const int kc    = (wv >> 1) * 2 + (lane & 1);  // 0..7 k-chunk
    const int rg    = lane >> 1;             // 0..31 row-group (2 rows)
    const int kbase = kc << 5;

    // ---- weights -> VGPRs as f32x2 pairs (same 128 VGPRs) ----
    f32x2 wih2[32], whh2[32];
    #pragma unroll
    for (int i = 0; i < 2; ++i) {
        int lr = rg * 2 + i;
        long grow = (long)((lr >> 4) * HH + j0 + (lr & 15));
        const float4* wi = (const float4*)(W_ih + grow * EE + kbase);
        const float4* wh = (const float4*)(W_hh + grow * EE + kbase);
        #pragma unroll
        for (int mi = 0; mi < 8; ++mi) {
            float4 a = wi[mi];
            float4 b = wh[mi];
            f32x2 t;
            t.x = a.x; t.y = a.y; wih2[(i * 8 + mi) * 2] = t;
            t.x = a.z; t.y = a.w; wih2[(i * 8 + mi) * 2 + 1] = t;
            t.x = b.x; t.y = b.y; whh2[(i * 8 + mi) * 2] = t;
            t.x = b.z; t.y = b.w; whh2[(i * 8 + mi) * 2 + 1] = t;
        }
    }

    // ---- epilogue state: wv0 -> A, wv1 -> B (lanes 0..31) ----
    const int eb  = (lane >> 4) & 1;  // batch 0..1 within context
    const int ejj = lane & 15;
    float bias_g[4]; float wz_r = 0.f; float c_reg = 0.f;
    if (wv < 2) {
        #pragma unroll
        for (int g = 0; g < 4; ++g)
            bias_g[g] = b_ih[g * HH + j0 + ejj] + b_hh[g * HH + j0 + ejj];
        wz_r = W_z[j0 + ejj];
    }

    // ---- self-spin mapping: lane polls ONE word = h[bp][kc*32 + (lane>>1)]
    const int pj    = (kc << 5) + (lane >> 1);   // word index in batch row
    const int pphys = kc * 36 + (lane >> 1);     // swizzled offset in h_sw row

    // ---- staging: wv4,5 -> A rows 0,1 ; wv6,7 -> B parity rows ----
    const bool stgA = (wv == 4 || wv == 5);
    const bool stgB = (wv == 6 || wv == 7);
    const int sphys = 4 * lane + ((lane >> 3) << 2);
    int tok_st = 0;

    if (stgA || stgB) {   // prologue: stage x(0); B goes to parity 0
        int base = stgA ? bA0 : bB0;
        int tk0 = sent[0 * NB + base + bp];
        f32x4 xv0 = ((const f32x4*)(emb + (long)tk0 * EE))[lane];
        int row = stgA ? bp : (2 + bp);
        *(f32x4*)(&x_sw[row * XLD + sphys]) = xv0;
        tok_st = sent[1 * NB + base + bp];
    }
    __syncthreads();

    for (int t = 0; t < TT; ++t) {
        const bool pf = (t + 1 < TT);
        const size_t parIn  = (size_t)(((t - 1) & 1) * NB);
        const size_t parOut = (size_t)((t & 1) * NB);
        const unsigned want = (unsigned)t;

        // ================= A window =================
        f32x4 xst;
        if ((stgA || stgB) && pf) {   // staging emb issue (cover >= 1 window)
            xst = ((const f32x4*)(emb + (long)tok_st * EE))[lane];
            if (t + 2 < TT)
                tok_st = sent[(t + 2) * NB + (stgA ? bA0 : bB0) + bp];
        }
        unsigned long long* hpA = hbuf + (parIn + bA0 + bp) * HH + pj;
        unsigned long long pv = 0;
        if (t > 0)   // own A-tag pre-issue (hidden under phase1_A)
            pv = __hip_atomic_load(hpA, __ATOMIC_RELAXED, __HIP_MEMORY_SCOPE_AGENT);

        if (t > 0 && wv == 2 && lane < 2) {   // part A(t-1)
            float s = 0.f;
            #pragma unroll
            for (int jj = 0; jj < 16; ++jj) s += p_s[lane * 16 + jj];
            part[((size_t)(t - 1) * PJ + js) * NB + bA0 + lane] = s;
        }

        f32x2 acc2[2][2];   // [row][lo/hi pair]
        #pragma unroll
        for (int i = 0; i < 2; ++i)
            #pragma unroll
            for (int j = 0; j < 2; ++j) { acc2[i][j].x = 0.f; acc2[i][j].y = 0.f; }

        {   // phase 1 A: x partials (packed)
            const float* xb = &x_sw[bp * XLD + kc * 36];
            #pragma unroll
            for (int mi = 0; mi < 8; ++mi) {
                float4 xv4 = *(const float4*)(xb + mi * 4);
                f32x2 xlo; xlo.x = xv4.x; xlo.y = xv4.y;
                f32x2 xhi; xhi.x = xv4.z; xhi.y = xv4.w;
                #pragma unroll
                for (int i = 0; i < 2; ++i) {
                    pkfma(acc2[i][0], wih2[(i * 8 + mi) * 2],     xlo);
                    pkfma(acc2[i][1], wih2[(i * 8 + mi) * 2 + 1], xhi);
                }
            }
        }
        if (t > 0) {   // self-spin A: check own word, fill own h_sw slot
            while ((unsigned)(pv >> 32) != want)
                pv = __hip_atomic_load(hpA, __ATOMIC_RELAXED, __HIP_MEMORY_SCOPE_AGENT);
            union { unsigned u; float f; } cu; cu.u = (unsigned)pv;
            h_sw[bp * XLD + pphys] = cu.f;
            // phase 2 A: h partials (same-wave fill -> lgkmcnt only)
            const float* hb = &h_sw[bp * XLD + kc * 36];
            #pragma unroll
            for (int mi = 0; mi < 8; ++mi) {
                float4 hv4 = *(const float4*)(hb + mi * 4);
                f32x2 hlo; hlo.x = hv4.x; hlo.y = hv4.y;
                f32x2 hhi; hhi.x = hv4.z; hhi.y = hv4.w;
                #pragma unroll
                for (int i = 0; i < 2; ++i) {
                    pkfma(acc2[i][0], whh2[(i * 8 + mi) * 2],     hlo);
                    pkfma(acc2[i][1], whh2[(i * 8 + mi) * 2 + 1], hhi);
                }
            }
        }
        {   // red_A write (same association as R18: (lo.x+lo.y)+(hi.x+hi.y))
            float2 v;
            v.x = (acc2[0][0].x + acc2[0][0].y) + (acc2[0][1].x + acc2[0][1].y);
            v.y = (acc2[1][0].x + acc2[1][0].y) + (acc2[1][1].x + acc2[1][1].y);
            *(float2*)(&red_s[kc * RS1 + bp * RS2 + rg * 2]) = v;
        }
        __syncthreads();   // S1: red_A ready

        // ================= B window =================
        unsigned long long* hpB = hbuf + (parIn + bB0 + bp) * HH + pj;
        unsigned long long qv = 0;
        if (t > 0)   // own B-tag pre-issue (publish was in t-1's tail)
            qv = __hip_atomic_load(hpB, __ATOMIC_RELAXED, __HIP_MEMORY_SCOPE_AGENT);

        if (wv == 0 && lane < 32) {   // epilogue A(t): overlaps others' phase1_B
            float sg[4];
            #pragma unroll
            for (int g = 0; g < 4; ++g) {
                float s = bias_g[g];
                #pragma unroll
                for (int k2 = 0; k2 < 8; ++k2)
                    s += red_s[k2 * RS1 + eb * RS2 + g * 16 + ejj];
                sg[g] = s;
            }
            float cn = sigf(sg[1]) * c_reg + sigf(sg[0]) * tanhf(sg[2]);
            float hn = sigf(sg[3]) * tanhf(cn);
            c_reg = cn;
            p_s[lane] = hn * wz_r;
            __hip_atomic_store(
                hbuf + (parOut + bA0 + eb) * HH + j0 + ejj,
                packh((unsigned)(t + 1), hn),
                __ATOMIC_RELAXED, __HIP_MEMORY_SCOPE_AGENT);
        }
        if (t > 0 && wv == 3 && lane < 2) {   // part B(t-1)
            float s = 0.f;
            #pragma unroll
            for (int jj = 0; jj < 16; ++jj) s += p_s[32 + lane * 16 + jj];
            part[((size_t)(t - 1) * PJ + js) * NB + bB0 + lane] = s;
        }

        #pragma unroll
        for (int i = 0; i < 2; ++i)
            #pragma unroll
            for (int j = 0; j < 2; ++j) { acc2[i][j].x = 0.f; acc2[i][j].y = 0.f; }

        {   // phase 1 B: x partials (parity buffer, packed)
            const float* xb = &x_sw[(2 + 2 * (t & 1) + bp) * XLD + kc * 36];
            #pragma unroll
            for (int mi = 0; mi < 8; ++mi) {
                float4 xv4 = *(const float4*)(xb + mi * 4);
                f32x2 xlo; xlo.x = xv4.x; xlo.y = xv4.y;
                f32x2 xhi; xhi.x = xv4.z; xhi.y = xv4.w;
                #pragma unroll
                for (int i = 0; i < 2; ++i) {
                    pkfma(acc2[i][0], wih2[(i * 8 + mi) * 2],     xlo);
                    pkfma(acc2[i][1], wih2[(i * 8 + mi) * 2 + 1], xhi);
                }
            }
        }
        if (t > 0) {   // self-spin B + fill + phase 2 B (packed)
            while ((unsigned)(qv >> 32) != want)
                qv = __hip_atomic_load(hpB, __ATOMIC_RELAXED, __HIP_MEMORY_SCOPE_AGENT);
            union { unsigned u; float f; } cu; cu.u = (unsigned)qv;
            h_sw[(2 + bp) * XLD + pphys] = cu.f;
            const float* hb = &h_sw[(2 + bp) * XLD + kc * 36];
            #pragma unroll
            for (int mi = 0; mi < 8; ++mi) {
                float4 hv4 = *(const float4*)(hb + mi * 4);
                f32x2 hlo; hlo.x = hv4.x; hlo.y = hv4.y;
                f32x2 hhi; hhi.x = hv4.z; hhi.y = hv4.w;
                #pragma unroll
                for (int i = 0; i < 2; ++i) {
                    pkfma(acc2[i][0], whh2[(i * 8 + mi) * 2],     hlo);
                    pkfma(acc2[i][1], whh2[(i * 8 + mi) * 2 + 1], hhi);
                }
            }
        }
        {   // red_B write
            float2 v;
            v.x = (acc2[0][0].x + acc2[0][0].y) + (acc2[0][1].x + acc2[0][1].y);
            v.y = (acc2[1][0].x + acc2[1][0].y) + (acc2[1][1].x + acc2[1][1].y);
            *(float2*)(&red_s[RBOFF + kc * RS1 + bp * RS2 + rg * 2]) = v;
        }
        if (stgA && pf)   // x_A(t+1): readers were pre-S1; next read post-S2
            *(f32x4*)(&x_sw[bp * XLD + sphys]) = xst;
        if (stgB && pf)   // x_B(t+1) into the OTHER parity buffer
            *(f32x4*)(&x_sw[(2 + 2 * ((t + 1) & 1) + bp) * XLD + sphys]) = xst;
        __syncthreads();   // S2: red_B ready; x staged

        // ================= tail: epilogue B(t), overlaps next A window ====
        if (wv == 1 && lane < 32) {
            float sg[4];
            #pragma unroll
            for (int g = 0; g < 4; ++g) {
                float s = bias_g[g];
                #pragma unroll
                for (int k2 = 0; k2 < 8; ++k2)
                    s += red_s[RBOFF + k2 * RS1 + eb * RS2 + g * 16 + ejj];
                sg[g] = s;
            }
            float cn = sigf(sg[1]) * c_reg + sigf(sg[0]) * tanhf(sg[2]);
            float hn = sigf(sg[3]) * tanhf(cn);
            c_reg = cn;
            p_s[32 + lane] = hn * wz_r;
            __hip_atomic_store(
                hbuf + (parOut + bB0 + eb) * HH + j0 + ejj,
                packh((unsigned)(t + 1), hn),
                __ATOMIC_RELAXED, __HIP_MEMORY_SCOPE_AGENT);
        }
    }

    // final part-sums (t = TT-1)
    __syncthreads();
    if (wv == 2 && lane < 2) {
        float s = 0.f;
        #pragma unroll
        for (int jj = 0; jj < 16; ++jj) s += p_s[lane * 16 + jj];
        part[((size_t)(TT - 1) * PJ + js) * NB + bA0 + lane] = s;
    }
    if (wv == 3 && lane < 2) {
        float s = 0.f;
        #pragma unroll
        for (int jj = 0; jj < 16; ++jj) s += p_s[32 + lane * 16 + jj];
        part[((size_t)(TT - 1) * PJ + js) * NB + bB0 + lane] = s;
    }
}

__global__ void pz_kernel(const float* __restrict__ part,
                          const float* __restrict__ noise,
                          const float* __restrict__ b_z,
                          float* __restrict__ out)
{
    int idx = blockIdx.x * blockDim.x + threadIdx.x;  // t*64 + b
    if (idx >= TT * NB) return;
    int t = idx >> 6, b = idx & 63;
    float s = b_z[0];
    #pragma unroll
    for (int jg = 0; jg < PJ; ++jg) s += part[(t * PJ + jg) * NB + b];
    float pz = 1.f / (1.f + expf(-s));
    out[idx] = pz;
    out[TT * NB + idx] = (noise[idx] < pz) ? 1.f : 0.f;
}

// One block per batch column: stable compaction of tokens where z==1.
__global__ void compact_kernel(const int* __restrict__ sent,
                               const float* __restrict__ zbuf,
                               float* __restrict__ rat,
                               float* __restrict__ zsz)
{
    __shared__ float rat_s[TT];
    __shared__ int scan_s[256];
    int b = blockIdx.x, tid = threadIdx.x;
    int zloc[8];
    int base = tid * 8;
    int c = 0;
    #pragma unroll
    for (int i = 0; i < 8; ++i) {
        zloc[i] = (zbuf[(base + i) * NB + b] != 0.f) ? 1 : 0;
        c += zloc[i];
    }
    scan_s[tid] = c;
    for (int i = tid; i < TT; i += 256) rat_s[i] = 0.f;
    __syncthreads();
    for (int off = 1; off < 256; off <<= 1) {
        int v = scan_s[tid];
        int add = (tid >= off) ? scan_s[tid - off] : 0;
        __syncthreads();
        scan_s[tid] = v + add;
        __syncthreads();
    }
    int total = scan_s[255];
    int pos = scan_s[tid] - c;  // exclusive prefix
    #pragma unroll
    for (int i = 0; i < 8; ++i) {
        if (zloc[i]) { rat_s[pos] = (float)sent[(base + i) * NB + b]; ++pos; }
    }
    __syncthreads();
    for (int i = tid; i < TT; i += 256) rat[i * NB + b] = rat_s[i];
    if (tid == 0) zsz[b] = (float)total;
}

extern "C" void kernel_launch(void* const* d_in, const int* in_sizes, int n_in,
                              void* d_out, int out_size, void* d_ws, size_t ws_size,
                              hipStream_t stream)
{
    const int*   sent  = (const int*)d_in[0];
    const float* noise = (const float*)d_in[1];
    const float* emb   = (const float*)d_in[2];
    const float* W_ih  = (const float*)d_in[3];
    const float* W_hh  = (const float*)d_in[4];
    const float* b_ih  = (const float*)d_in[5];
    const float* b_hh  = (const float*)d_in[6];
    const float* W_z   = (const float*)d_in[7];
    const float* b_z   = (const float*)d_in[8];
    float* out = (float*)d_out;

    char* ws = (char*)d_ws;
    unsigned long long* hbuf = (unsigned long long*)ws;     // 2*64*256*8 = 256 KB
    float* part = (float*)(ws + 262144);                    // 2048*16*64*4 = 8 MB

    // tags must start != any expected tag (1..2048)
    (void)hipMemsetAsync(hbuf, 0, 2 * NB * HH * sizeof(unsigned long long), stream);

    // ~30KB static + 64KB dynamic -> ~94KB -> exactly 1 WG/CU
    lstm_kernel<<<256, 512, 65536, stream>>>(sent, emb, W_ih, W_hh, b_ih, b_hh,
                                             W_z, hbuf, part);
    pz_kernel<<<(TT * NB) / 256, 256, 0, stream>>>(part, noise, b_z, out);
    compact_kernel<<<NB, 256, 0, stream>>>(sent, out + TT * NB,
                                           out + 2 * TT * NB, out + 3 * TT * NB);
}